// Round 5
// baseline (396.989 us; speedup 1.0000x reference)
//
#include <hip/hip_runtime.h>

#define DIM 128
#define NS  12   // SAMPLE

typedef _Float16 f16x8 __attribute__((ext_vector_type(8)));
typedef float    f32x4 __attribute__((ext_vector_type(4)));

// v_mfma_f32_16x16x32_f16 (gfx950-native): D[i][j] += sum_k A[i][k]*B[k][j]
// A: lane l holds A[l&15][8*(l>>4)+j]; B: lane l holds B[8*(l>>4)+j][l&15]
// C/D: lane l holds C[4*(l>>4)+r][l&15] (m89-verified, dtype-independent)
#define MFMA32(a, b, c) __builtin_amdgcn_mfma_f32_16x16x32_f16((a), (b), (c), 0, 0, 0)

struct __align__(16) SMem {
    // per-unit feat rows, XOR-swizzled: half idx = m*128 + (k ^ (m<<3))
    _Float16 feat[2][16 * DIM];   // 8 KB
    float agg1[NS][DIM];          // 6 KB, shared across units
    float part[2][2][16];         // [unit][wid][row]
    float nwsh[2][16];            // per-unit neighbor weights (pad zeroed)
    float fin[2][DIM];            // final-mix vectors
};

template <int CTRL>
__device__ __forceinline__ float dpp_add(float v) {
    // VALU-pipe cross-lane add (no DS traffic)
    int t = __builtin_amdgcn_update_dpp(0, __float_as_int(v), CTRL, 0xf, 0xf, false);
    return v + __int_as_float(t);
}

// ---------------------------------------------------------------------------
// One aggregate step for one 2-wave unit. Logits via MFMA (f16 in, f32 acc);
// softmax + PV stay f32. Barrier contract: sync1 after stage, sync2 after
// part-write; BOTH units call this the same number of times in the same
// sequence (block-wide barriers).
// ---------------------------------------------------------------------------
__device__ __forceinline__ float agg_mfma(const int d, const int wid, const int g,
                                          const int mm, const float ih,
                                          const float* __restrict__ nbv,
                                          const f16x8 (&bf)[4][4],
                                          const f32x4 w1bf, const f32x4 w2f,
                                          _Float16* __restrict__ featu,
                                          float (*__restrict__ partu)[16],
                                          const float* __restrict__ nwshu) {
    // ---- stage feat rows 0..11 as f16, swizzled ----
#pragma unroll
    for (int s = 0; s < NS; ++s)
        featu[s * DIM + (d ^ (s << 3))] = (_Float16)(ih * nbv[s]);
    __syncthreads();   // sync1

    // ---- logits via MFMA: c{nt}[r] = logits[4g+r][wid*64+nt*16+mm] ----
    const f32x4 zero = {0.f, 0.f, 0.f, 0.f};
    f32x4 c0 = zero, c1 = zero, c2 = zero, c3 = zero;
    const int abase = mm * DIM;
    const int mx = mm << 3;
#pragma unroll
    for (int kk = 0; kk < 4; ++kk) {   // K = 4 x 32
        const f16x8 a =
            *(const f16x8*)&featu[abase + (((kk << 5) + (g << 3)) ^ mx)];
        c0 = MFMA32(a, bf[kk][0], c0);
        c1 = MFMA32(a, bf[kk][1], c1);
        c2 = MFMA32(a, bf[kk][2], c2);
        c3 = MFMA32(a, bf[kk][3], c3);
    }

    // ---- bias + leaky_relu(0.2) + w2 weighting ----
    const f32x4 nw4 = *(const f32x4*)&nwshu[g * 4];
    float val[4];
#pragma unroll
    for (int r = 0; r < 4; ++r) {
        float t0 = c0[r] + nw4[r] * w1bf[0];
        float t1 = c1[r] + nw4[r] * w1bf[1];
        float t2 = c2[r] + nw4[r] * w1bf[2];
        float t3 = c3[r] + nw4[r] * w1bf[3];
        t0 = t0 > 0.f ? t0 : 0.2f * t0;
        t1 = t1 > 0.f ? t1 : 0.2f * t1;
        t2 = t2 > 0.f ? t2 : 0.2f * t2;
        t3 = t3 > 0.f ? t3 : 0.2f * t3;
        val[r] = fmaf(t0, w2f[0], fmaf(t1, w2f[1], fmaf(t2, w2f[2], t3 * w2f[3])));
    }

    // ---- reduce over the 16 cols of this lane group: DPP butterfly ----
#pragma unroll
    for (int r = 0; r < 4; ++r) {
        val[r] = dpp_add<0xB1>(val[r]);    // quad_perm [1,0,3,2]
        val[r] = dpp_add<0x4E>(val[r]);    // quad_perm [2,3,0,1]
        val[r] = dpp_add<0x124>(val[r]);   // row_ror:4
        val[r] = dpp_add<0x128>(val[r]);   // row_ror:8
    }
    if (mm == 0) {
        const f32x4 v = {val[0], val[1], val[2], val[3]};
        *(f32x4*)&partu[wid][g * 4] = v;
    }
    __syncthreads();   // sync2

    // ---- softmax over 12 logits (redundant per thread) + PV in f32 ----
    const f32x4 pa0 = *(const f32x4*)&partu[0][0];
    const f32x4 pa1 = *(const f32x4*)&partu[0][4];
    const f32x4 pa2 = *(const f32x4*)&partu[0][8];
    const f32x4 pb0 = *(const f32x4*)&partu[1][0];
    const f32x4 pb1 = *(const f32x4*)&partu[1][4];
    const f32x4 pb2 = *(const f32x4*)&partu[1][8];
    const f32x4 q0 = pa0 + pb0, q1 = pa1 + pb1, q2 = pa2 + pb2;
    float cc[NS] = {q0[0], q0[1], q0[2], q0[3], q1[0], q1[1], q1[2], q1[3],
                    q2[0], q2[1], q2[2], q2[3]};
    float m = -1e30f;
#pragma unroll
    for (int s = 0; s < NS; ++s) m = fmaxf(m, cc[s]);
    float sum = 0.f;
#pragma unroll
    for (int s = 0; s < NS; ++s) { cc[s] = __expf(cc[s] - m); sum += cc[s]; }
    const float inv = 1.f / sum;
    float o0 = 0.f, o1 = 0.f, o2 = 0.f, o3 = 0.f;
#pragma unroll
    for (int s = 0; s < NS; s += 4) {
        o0 = fmaf(cc[s + 0], nbv[s + 0], o0);
        o1 = fmaf(cc[s + 1], nbv[s + 1], o1);
        o2 = fmaf(cc[s + 2], nbv[s + 2], o2);
        o3 = fmaf(cc[s + 3], nbv[s + 3], o3);
    }
    return ((o0 + o1) + (o2 + o3)) * inv;
}

// ---------------------------------------------------------------------------
// One block per node n, 256 threads = 2 units x 2 waves.
// Unit u handles agg1[u*6 .. u*6+5]; both units redundantly compute agg0 and
// agg2 (keeps block-wide barrier counts uniform). Neighbor loads for
// aggregate j+1 are issued before computing aggregate j (register double
// buffer, static indexing), hiding ~900-cy HBM latency under compute.
// __launch_bounds__(256,1): VGPR cap 128 (fitted: cap = 512/(arg*block_waves)).
// ---------------------------------------------------------------------------
__global__ __launch_bounds__(256, 1) void fused_kernel(
    const float* __restrict__ hidden, const float* __restrict__ nh1,
    const float* __restrict__ nh2, const float* __restrict__ nw0,
    const float* __restrict__ nw1, const float* __restrict__ w1,
    const float* __restrict__ w2, const float* __restrict__ w3,
    const float* __restrict__ w4, const float* __restrict__ sv,
    float* __restrict__ out) {
    const int n = blockIdx.x;
    const int tid = threadIdx.x;
    const int u = tid >> 7;          // unit 0/1
    const int d = tid & 127;         // channel within unit
    const int wid = (tid >> 6) & 1;  // wave within unit
    const int l = tid & 63, g = l >> 4, mm = l & 15;
    __shared__ SMem sm;

    // pad rows (A rows 12..15 must be 0) + nwsh for agg0; first sync1 publishes
#pragma unroll
    for (int m = NS; m < 16; ++m)
        sm.feat[u][m * DIM + (d ^ (m << 3))] = (_Float16)0.f;
    if (d < 16) sm.nwsh[u][d] = (d < NS) ? nw0[n * NS + d] : 0.f;

    // ---- agg0 inputs + prefetch of this unit's first agg1 ----
    const float ih0 = hidden[n * DIM + d];
    float nbva[NS];
#pragma unroll
    for (int s = 0; s < NS; ++s) nbva[s] = nh1[(size_t)(n * NS + s) * DIM + d];

    const int j0 = u * 6;
    float nbvb[NS];
    {
        const size_t kb = (size_t)(n * NS + j0);
#pragma unroll
        for (int s = 0; s < NS; ++s) nbvb[s] = nh2[(kb * NS + s) * DIM + d];
    }
    float ihb = nh1[(size_t)(n * NS + j0) * DIM + d];

    // ---- w1 B-fragments (f16) + bias/w2 fragments (f32), per wave ----
    f16x8 bf[4][4];
    const int colb = wid * 64 + mm;
#pragma unroll
    for (int kk = 0; kk < 4; ++kk) {
#pragma unroll
        for (int nt = 0; nt < 4; ++nt) {
            f16x8 t;
#pragma unroll
            for (int j = 0; j < 8; ++j)
                t[j] = (_Float16)w1[(kk * 32 + g * 8 + j) * DIM + colb + nt * 16];
            bf[kk][nt] = t;
        }
    }
    f32x4 w1bf, w2f;
#pragma unroll
    for (int nt = 0; nt < 4; ++nt) {
        w1bf[nt] = w1[DIM * DIM + colb + nt * 16];  // bias row (f32)
        w2f[nt]  = w2[colb + nt * 16];
    }

    // ---- agg0 (both units, redundant) ----
    const float agg0 = agg_mfma(d, wid, g, mm, ih0, nbva, bf, w1bf, w2f,
                                sm.feat[u], sm.part[u], sm.nwsh[u]);

    // ---- this unit's 6 agg1's, register-double-buffered prefetch ----
#pragma unroll 1
    for (int jj = 0; jj < 6; jj += 2) {
        float iha;
        {   // prefetch j0+jj+1 into nbva (in flight during the next call)
            const size_t ka = (size_t)(n * NS + j0 + jj + 1);
#pragma unroll
            for (int s = 0; s < NS; ++s) nbva[s] = nh2[(ka * NS + s) * DIM + d];
            iha = nh1[ka * DIM + d];
        }
        if (d < NS) sm.nwsh[u][d] = nw1[(size_t)(n * NS + j0 + jj) * NS + d];
        sm.agg1[j0 + jj][d] = agg_mfma(d, wid, g, mm, ihb, nbvb, bf, w1bf, w2f,
                                       sm.feat[u], sm.part[u], sm.nwsh[u]);

        if (jj + 2 < 6) {  // prefetch j0+jj+2 into nbvb
            const size_t kb2 = (size_t)(n * NS + j0 + jj + 2);
#pragma unroll
            for (int s = 0; s < NS; ++s) nbvb[s] = nh2[(kb2 * NS + s) * DIM + d];
            ihb = nh1[kb2 * DIM + d];
        }
        if (d < NS) sm.nwsh[u][d] = nw1[(size_t)(n * NS + j0 + jj + 1) * NS + d];
        sm.agg1[j0 + jj + 1][d] = agg_mfma(d, wid, g, mm, iha, nbva, bf, w1bf,
                                           w2f, sm.feat[u], sm.part[u], sm.nwsh[u]);
    }

    __syncthreads();  // all 12 agg1 rows visible to both units

    // ---- agg2 (both units, redundant; items from sm.agg1) ----
    if (d < NS) sm.nwsh[u][d] = nw0[n * NS + d];
#pragma unroll
    for (int s = 0; s < NS; ++s) nbvb[s] = sm.agg1[s][d];
    const float agg2 = agg_mfma(d, wid, g, mm, agg0, nbvb, bf, w1bf, w2f,
                                sm.feat[u], sm.part[u], sm.nwsh[u]);

    // ---- final mix (unit 0 only; full f32) ----
    const float ah = sv[0] * agg0 + sv[1] * agg2;
    if (tid < DIM) { sm.fin[0][d] = ih0; sm.fin[1][d] = ah; }
    __syncthreads();
    if (tid < DIM) {
        float t0 = 0.f, t1 = 0.f, t2 = 0.f, t3 = 0.f;
#pragma unroll
        for (int k = 0; k < DIM; k += 4) {
            const f32x4 h4 = *(const f32x4*)&sm.fin[0][k];
            const f32x4 a4 = *(const f32x4*)&sm.fin[1][k];
            t0 = fmaf(h4[0], w3[(k + 0) * DIM + d], t0);
            t1 = fmaf(h4[1], w3[(k + 1) * DIM + d], t1);
            t2 = fmaf(h4[2], w3[(k + 2) * DIM + d], t2);
            t3 = fmaf(h4[3], w3[(k + 3) * DIM + d], t3);
            t0 = fmaf(a4[0], w4[(k + 0) * DIM + d], t0);
            t1 = fmaf(a4[1], w4[(k + 1) * DIM + d], t1);
            t2 = fmaf(a4[2], w4[(k + 2) * DIM + d], t2);
            t3 = fmaf(a4[3], w4[(k + 3) * DIM + d], t3);
        }
        const float t = (t0 + t1) + (t2 + t3);
        const float w = 1.f / (1.f + __expf(-t));
        out[n * DIM + d] = (1.f - w) * ih0 + w * ah;
    }
}

extern "C" void kernel_launch(void* const* d_in, const int* in_sizes, int n_in,
                              void* d_out, int out_size, void* d_ws, size_t ws_size,
                              hipStream_t stream) {
    const float* hidden = (const float*)d_in[0];  // [64,50,128]
    const float* nh1    = (const float*)d_in[1];  // [64,600,128]
    const float* nh2    = (const float*)d_in[2];  // [64,7200,128]
    const float* nw0    = (const float*)d_in[3];  // [64,50,12]
    const float* nw1    = (const float*)d_in[4];  // [64,600,12]
    const float* w1     = (const float*)d_in[5];  // [129,128]
    const float* w2     = (const float*)d_in[6];  // [128,1]
    const float* w3     = (const float*)d_in[7];  // [128,128]
    const float* w4     = (const float*)d_in[8];  // [128,128]
    const float* sv     = (const float*)d_in[9];  // [2,1]

    fused_kernel<<<3200, 256, 0, stream>>>(hidden, nh1, nh2, nw0, nw1, w1, w2,
                                           w3, w4, sv, (float*)d_out);
}